// Round 1
// baseline (313.178 us; speedup 1.0000x reference)
//
#include <hip/hip_runtime.h>
#include <hip/hip_bf16.h>

// ---------------------------------------------------------------------------
// SelfAttentionHybrid: single-head attention, B=4 S=2048 E=1024, fp32 in/out.
// R7: add gemm256_bt — 256x256 tile, BK=64, 512 thr / 8 waves (2Mx4N),
// 8-phase-per-2-K-tiles schedule with counted vmcnt (T3+T4), raw s_barrier
// (no vmcnt(0) drain), setprio around MFMA clusters (T5), chunk-XOR LDS
// swizzle (T2 analog, same involution as the 128^2 kernel).
// Used for QKV (384 blocks) and scores (256 blocks). PV + out GEMMs keep the
// 128^2 kernel (their 256^2 grids would be 128 blocks = half the CUs idle).
//
// gemm256 schedule per K-tile kt (buf c = kt&1), derived so each LDS region
// is refilled for tile kt+2 in the phase AFTER its last reader:
//   ph0: ds_read Aq0(8)+Bq0(4);           barrier; MFMA accM0xN0; barrier
//   ph1: ds_read Bq1(4);                  barrier; MFMA accM0xN1; barrier
//   ph2: ds_read Aq1(8); issue B(kt+2);   barrier; MFMA accM1xN1; barrier
//   ph3: issue A(kt+2); MFMA accM1xN0; vmcnt(8);                  barrier
// Boundary invariant: tile kt+1's 8 loads (issued at kt-1 ph2/ph3) are the
// oldest outstanding; vmcnt(8) retires them while kt+2's 8 stay in flight.
// Prologue stages tiles 0 and 1 (16 loads), vmcnt(8) retires tile 0.
// ---------------------------------------------------------------------------

typedef __bf16 bf16_t;
typedef __bf16 bf16x8 __attribute__((ext_vector_type(8)));
typedef __bf16 bf16x4 __attribute__((ext_vector_type(4)));
typedef float  f32x16 __attribute__((ext_vector_type(16)));
typedef float  f32x4  __attribute__((ext_vector_type(4)));

__device__ __forceinline__ void async_copy16(const void* g, void* l) {
  __builtin_amdgcn_global_load_lds(
      (const __attribute__((address_space(1))) void*)g,
      (__attribute__((address_space(3))) void*)l, 16, 0, 0);
}

// raw workgroup barrier: NO vmcnt/lgkmcnt drain (unlike __syncthreads),
// with compiler-level memory fences so LDS ops can't be moved across.
__device__ __forceinline__ void wg_barrier() {
  asm volatile("" ::: "memory");
  __builtin_amdgcn_s_barrier();
  asm volatile("" ::: "memory");
}

__device__ __forceinline__ f32x4 mfma16(bf16x8 a, bf16x8 b, f32x4 c) {
  return __builtin_amdgcn_mfma_f32_16x16x32_bf16(a, b, c, 0, 0, 0);
}

__device__ __forceinline__ void store_out(float* p, float v)  { *p = v; }
__device__ __forceinline__ void store_out(bf16_t* p, float v) { *p = (bf16_t)v; }

#define BM 128
#define BN 128
#define BKT 64

// ---------------------------------------------------------------------------
// gemm256_bt: C[M,N] = A[M,K](lda) x B[N,K](ldb)^T * scale + bias.
// 512 thr = 8 waves (2Mx4N); wave tile 128x64 = 8x4 frags of 16x16x32 MFMA.
// A-frag: row = lane&15, k = (lane>>4)*8+j. C/D: col = lane&15,
// row = (lane>>4)*4 + reg (guide-verified m89/m91 mappings).
// LDS [2 buf][256 rows][64 bf16] per matrix; slot (r,cc) holds global chunk
// cc^(r&7); reads use slot = kc^(r&7) (involution; per-16-lane cohort the 8
// slots are hit 2x each -> minimum aliasing).
// Requires M%256==0, N%256==0, K%64==0, K>=128, gridDim.y%8==0.
// ---------------------------------------------------------------------------
template <typename OutT, int NBIAS>
__global__ __launch_bounds__(512, 2) void gemm256_bt(
    const bf16_t* __restrict__ A, const bf16_t* __restrict__ B,
    OutT* __restrict__ C,
    const float* __restrict__ b0, const float* __restrict__ b1,
    const float* __restrict__ b2,
    int M, int N, int K, int lda, int ldb, int ldc, float scale,
    long long strideA, long long strideB, long long strideC) {
  const int z = blockIdx.z;
  A += (long long)z * strideA;
  B += (long long)z * strideB;
  C += (long long)z * strideC;

  // L2 supertile remap: 8 y-tiles per supertile, y-fastest inside.
  int bx = blockIdx.x, by = blockIdx.y;
  {
    const int GX  = gridDim.x;
    const int id  = by * GX + bx;
    const int per = GX * 8;
    const int grp = id / per;
    const int rem = id - grp * per;
    by = grp * 8 + (rem & 7);
    bx = rem >> 3;
  }

  __shared__ __align__(16) bf16_t As[2 * 256 * 64];  // 64 KB
  __shared__ __align__(16) bf16_t Bs[2 * 256 * 64];  // 64 KB

  const int t    = threadIdx.x;
  const int lane = t & 63;
  const int w    = t >> 6;
  const int wm   = w & 1;    // M-half of output tile
  const int wn   = w >> 1;   // N-quarter of output tile
  const int g    = lane >> 4;
  const int l7   = lane & 7;
  const int r15  = lane & 15;
  const int tileM = by * 256;
  const int tileN = bx * 256;

  // staging constants: thread covers chunks t and t+512 of each half-tile
  const int row0 = t >> 3;                    // 0..63
  const int gcc  = (t & 7) ^ (row0 & 7);      // swizzled source chunk
  const int dstb = (t & ~63) * 8;             // wave-uniform LDS base (elems)

  // read constants
  const int sw0 = ((0 + g) ^ l7) * 8;         // k-slice 0 chunk offset (elems)
  const int sw1 = ((4 + g) ^ l7) * 8;         // k-slice 1
  const int aRow = (wm * 128 + r15) * 64;
  const int bRow = (wn * 64 + r15) * 64;

  const int NT = K >> 6;

  f32x4 acc[8][4] = {};

  auto stageA = [&](int kt, int h) {
    const int cb = (kt & 1) * 16384;
    const bf16_t* src =
        A + (long long)(tileM + h * 128 + row0) * lda + kt * 64 + gcc * 8;
    bf16_t* dst = &As[cb + h * 8192 + dstb];
    async_copy16(src, dst);
    async_copy16(src + (long long)64 * lda, dst + 4096);
  };
  auto stageB = [&](int kt, int h) {
    const int cb = (kt & 1) * 16384;
    const bf16_t* src =
        B + (long long)(tileN + h * 128 + row0) * ldb + kt * 64 + gcc * 8;
    bf16_t* dst = &Bs[cb + h * 8192 + dstb];
    async_copy16(src, dst);
    async_copy16(src + (long long)64 * ldb, dst + 4096);
  };

  // prologue: tiles 0 (oldest 8 loads) and 1; retire tile 0, keep 1 in flight
  stageA(0, 0); stageA(0, 1); stageB(0, 0); stageB(0, 1);
  stageA(1, 0); stageA(1, 1); stageB(1, 0); stageB(1, 1);
  asm volatile("s_waitcnt vmcnt(8)" ::: "memory");
  wg_barrier();

  bf16x8 a[4][2], bq[2][2][2];

  for (int kt = 0; kt < NT; ++kt) {
    const int cb = (kt & 1) * 16384;
    const int k2 = kt + 2;

    // ---- phase 0: read Aq0 + Bq0; MFMA M-quad0 x N-quad0
#pragma unroll
    for (int i = 0; i < 4; ++i) {
      a[i][0] = *(const bf16x8*)&As[cb + aRow + i * 1024 + sw0];
      a[i][1] = *(const bf16x8*)&As[cb + aRow + i * 1024 + sw1];
    }
#pragma unroll
    for (int j = 0; j < 2; ++j) {
      bq[0][j][0] = *(const bf16x8*)&Bs[cb + bRow + j * 1024 + sw0];
      bq[0][j][1] = *(const bf16x8*)&Bs[cb + bRow + j * 1024 + sw1];
    }
    wg_barrier();
    __builtin_amdgcn_s_setprio(1);
#pragma unroll
    for (int i = 0; i < 4; ++i)
#pragma unroll
      for (int j = 0; j < 2; ++j) {
        acc[i][j] = mfma16(a[i][0], bq[0][j][0], acc[i][j]);
        acc[i][j] = mfma16(a[i][1], bq[0][j][1], acc[i][j]);
      }
    __builtin_amdgcn_s_setprio(0);
    wg_barrier();

    // ---- phase 1: read Bq1; MFMA M-quad0 x N-quad1
#pragma unroll
    for (int j = 0; j < 2; ++j) {
      bq[1][j][0] = *(const bf16x8*)&Bs[cb + bRow + 2048 + j * 1024 + sw0];
      bq[1][j][1] = *(const bf16x8*)&Bs[cb + bRow + 2048 + j * 1024 + sw1];
    }
    wg_barrier();
    __builtin_amdgcn_s_setprio(1);
#pragma unroll
    for (int i = 0; i < 4; ++i)
#pragma unroll
      for (int j = 0; j < 2; ++j) {
        acc[i][2 + j] = mfma16(a[i][0], bq[1][j][0], acc[i][2 + j]);
        acc[i][2 + j] = mfma16(a[i][1], bq[1][j][1], acc[i][2 + j]);
      }
    __builtin_amdgcn_s_setprio(0);
    wg_barrier();

    // ---- phase 2: read Aq1 (B-slots of this buf now dead -> issue B(kt+2))
#pragma unroll
    for (int i = 0; i < 4; ++i) {
      a[i][0] = *(const bf16x8*)&As[cb + aRow + 4096 + i * 1024 + sw0];
      a[i][1] = *(const bf16x8*)&As[cb + aRow + 4096 + i * 1024 + sw1];
    }
    if (k2 < NT) { stageB(k2, 0); stageB(k2, 1); }
    wg_barrier();
    __builtin_amdgcn_s_setprio(1);
#pragma unroll
    for (int i = 0; i < 4; ++i)
#pragma unroll
      for (int j = 0; j < 2; ++j) {
        acc[4 + i][2 + j] = mfma16(a[i][0], bq[1][j][0], acc[4 + i][2 + j]);
        acc[4 + i][2 + j] = mfma16(a[i][1], bq[1][j][1], acc[4 + i][2 + j]);
      }
    __builtin_amdgcn_s_setprio(0);
    wg_barrier();

    // ---- phase 3: A-slots dead -> issue A(kt+2); reg-only MFMA; counted wait
    if (k2 < NT) { stageA(k2, 0); stageA(k2, 1); }
    __builtin_amdgcn_s_setprio(1);
#pragma unroll
    for (int i = 0; i < 4; ++i)
#pragma unroll
      for (int j = 0; j < 2; ++j) {
        acc[4 + i][j] = mfma16(a[i][0], bq[0][j][0], acc[4 + i][j]);
        acc[4 + i][j] = mfma16(a[i][1], bq[0][j][1], acc[4 + i][j]);
      }
    __builtin_amdgcn_s_setprio(0);
    // retire tile kt+1's loads; kt+2's 8 loads stay in flight (never drain
    // mid-loop; full drain only when no kt+2 was issued).
    if (k2 < NT) asm volatile("s_waitcnt vmcnt(8)" ::: "memory");
    else         asm volatile("s_waitcnt vmcnt(0)" ::: "memory");
    wg_barrier();
  }

  // epilogue: 16x16 C map: col = lane&15, row = (lane>>4)*4 + r
#pragma unroll
  for (int j = 0; j < 4; ++j) {
    const int col = tileN + wn * 64 + j * 16 + r15;
    float bv = 0.f;
    if (NBIAS == 1) bv = b0[col];
    if (NBIAS == 3) {
      const float* bp = col < 1024 ? b0 : (col < 2048 ? b1 : b2);
      bv = bp[col & 1023];
    }
#pragma unroll
    for (int i = 0; i < 8; ++i) {
      const int rowb = tileM + wm * 128 + i * 16 + g * 4;
#pragma unroll
      for (int r = 0; r < 4; ++r)
        store_out(&C[(long long)(rowb + r) * ldc + col],
                  acc[i][j][r] * scale + bv);
    }
  }
}

// ---------------------------------------------------------------------------
// 128^2 kernel (R6) — kept for PV and output GEMMs (their 256^2 grids would
// be 128 blocks = half the CUs).
// ---------------------------------------------------------------------------
template <typename OutT, int NBIAS>
__global__ __launch_bounds__(256) void gemm_bt(
    const bf16_t* __restrict__ A, const bf16_t* __restrict__ B,
    OutT* __restrict__ C,
    const float* __restrict__ b0, const float* __restrict__ b1,
    const float* __restrict__ b2,
    int M, int N, int K, int lda, int ldb, int ldc, float scale,
    long long strideA, long long strideB, long long strideC) {
  const int z = blockIdx.z;
  A += (long long)z * strideA;
  B += (long long)z * strideB;
  C += (long long)z * strideC;

  int bx = blockIdx.x, by = blockIdx.y;
  {
    const int GX  = gridDim.x;
    const int id  = by * GX + bx;
    const int per = GX * 8;
    const int grp = id / per;
    const int rem = id - grp * per;
    by = grp * 8 + (rem & 7);
    bx = rem >> 3;
  }

  __shared__ __align__(16) bf16_t As[BM * BKT];  // 16 KB
  __shared__ __align__(16) bf16_t Bs[BN * BKT];  // 16 KB

  const int t    = threadIdx.x;
  const int lane = t & 63;
  const int w    = t >> 6;
  const int wm   = w & 1;
  const int wn   = w >> 1;
  const int tileM = by * BM;
  const int tileN = bx * BN;

  f32x16 acc[2][2] = {};

  for (int k0 = 0; k0 < K; k0 += BKT) {
#pragma unroll
    for (int i = 0; i < 4; ++i) {
      const int c   = t + 256 * i;
      const int row = c >> 3;
      const int cc  = c & 7;
      const int gcc = cc ^ (row & 7);
      const int ldsbase = ((t & ~63) + 256 * i) * 8;
      async_copy16(A + (long long)(tileM + row) * lda + k0 + gcc * 8, &As[ldsbase]);
      async_copy16(B + (long long)(tileN + row) * ldb + k0 + gcc * 8, &Bs[ldsbase]);
    }
    __syncthreads();

#pragma unroll
    for (int s = 0; s < 4; ++s) {
      const int kc = s + 4 * (lane >> 5);
      bf16x8 af[2], bfr[2];
#pragma unroll
      for (int ti = 0; ti < 2; ++ti) {
        const int row = wm * 64 + ti * 32 + (lane & 31);
        af[ti] = *(const bf16x8*)&As[row * BKT + ((kc ^ (row & 7)) * 8)];
      }
#pragma unroll
      for (int tj = 0; tj < 2; ++tj) {
        const int row = wn * 64 + tj * 32 + (lane & 31);
        bfr[tj] = *(const bf16x8*)&Bs[row * BKT + ((kc ^ (row & 7)) * 8)];
      }
#pragma unroll
      for (int ti = 0; ti < 2; ++ti)
#pragma unroll
        for (int tj = 0; tj < 2; ++tj)
          acc[ti][tj] = __builtin_amdgcn_mfma_f32_32x32x16_bf16(
              af[ti], bfr[tj], acc[ti][tj], 0, 0, 0);
    }
    __syncthreads();
  }

#pragma unroll
  for (int tj = 0; tj < 2; ++tj) {
    const int col = tileN + wn * 64 + tj * 32 + (lane & 31);
    float bv = 0.f;
    if (NBIAS == 1) bv = b0[col];
    if (NBIAS == 3) {
      const float* bp = col < 1024 ? b0 : (col < 2048 ? b1 : b2);
      bv = bp[col & 1023];
    }
#pragma unroll
    for (int ti = 0; ti < 2; ++ti) {
      const int rowb = tileM + wm * 64 + ti * 32 + 4 * (lane >> 5);
#pragma unroll
      for (int r = 0; r < 16; ++r) {
        const int row = rowb + (r & 3) + 8 * (r >> 2);
        store_out(&C[(long long)row * ldc + col], acc[ti][tj][r] * scale + bv);
      }
    }
  }
}

// ---------------------------------------------------------------------------
// fused cast: all 4 weights + x in one dispatch (flat grid, region decode).
// ---------------------------------------------------------------------------
__global__ __launch_bounds__(256) void cast_all(
    const float4* __restrict__ w0, const float4* __restrict__ w1,
    const float4* __restrict__ w2, const float4* __restrict__ w3,
    const float4* __restrict__ x,
    bf16x4* __restrict__ wdst, bf16x4* __restrict__ xdst) {
  const int N4W = 1 << 18;  // 1024*1024/4
  const int id = blockIdx.x * 256 + threadIdx.x;
  const float4* src;
  bf16x4* dst;
  if (id < 4 * N4W) {
    const int z = id >> 18;
    src = (z == 0 ? w0 : z == 1 ? w1 : z == 2 ? w2 : w3) + (id & (N4W - 1));
    dst = wdst + id;
  } else {
    const int i = id - 4 * N4W;
    src = x + i;
    dst = xdst + i;
  }
  const float4 v = *src;
  bf16x4 o;
  o[0] = (bf16_t)v.x; o[1] = (bf16_t)v.y; o[2] = (bf16_t)v.z; o[3] = (bf16_t)v.w;
  *dst = o;
}

// ---------------------------------------------------------------------------
// bf16 transpose [R,C](ldin) -> [C,R], batched via blockIdx.z
// ---------------------------------------------------------------------------
__global__ __launch_bounds__(256) void transpose_bf16(
    const bf16_t* __restrict__ in, bf16_t* __restrict__ out, int R, int C,
    int ldin, long long sIn, long long sOut) {
  in  += (long long)blockIdx.z * sIn;
  out += (long long)blockIdx.z * sOut;
  __shared__ bf16_t tile[32][33];
  const int tx = threadIdx.x, ty = threadIdx.y;
  const int x = blockIdx.x * 32 + tx;
  const int y0 = blockIdx.y * 32;
#pragma unroll
  for (int j = 0; j < 32; j += 8)
    tile[ty + j][tx] = in[(long long)(y0 + ty + j) * ldin + x];
  __syncthreads();
  const int x2 = y0 + tx;
  const int y2 = blockIdx.x * 32;
#pragma unroll
  for (int j = 0; j < 32; j += 8)
    out[(long long)(y2 + ty + j) * R + x2] = tile[tx][ty + j];
}

// ---------------------------------------------------------------------------
// row softmax: 2048-wide rows, 256 threads x 8 elems
// ---------------------------------------------------------------------------
__global__ __launch_bounds__(256) void softmax_rows(
    const bf16_t* __restrict__ S, bf16_t* __restrict__ P, int cols) {
  const long long row = blockIdx.x;
  const bf16x8* inp = (const bf16x8*)(S + row * cols);
  bf16x8* outp      = (bf16x8*)(P + row * cols);
  const int t = threadIdx.x;
  const int w = t >> 6, lane = t & 63;

  const bf16x8 v = inp[t];
  float f[8];
#pragma unroll
  for (int j = 0; j < 8; ++j) f[j] = (float)v[j];

  float m = f[0];
#pragma unroll
  for (int j = 1; j < 8; ++j) m = fmaxf(m, f[j]);
#pragma unroll
  for (int off = 32; off > 0; off >>= 1) m = fmaxf(m, __shfl_xor(m, off));

  __shared__ float red[8];
  if (lane == 0) red[w] = m;
  __syncthreads();
  m = fmaxf(fmaxf(red[0], red[1]), fmaxf(red[2], red[3]));

  float e[8], sum = 0.f;
#pragma unroll
  for (int j = 0; j < 8; ++j) { e[j] = __expf(f[j] - m); sum += e[j]; }
#pragma unroll
  for (int off = 32; off > 0; off >>= 1) sum += __shfl_xor(sum, off);
  if (lane == 0) red[4 + w] = sum;
  __syncthreads();
  sum = red[4] + red[5] + red[6] + red[7];

  const float inv = 1.f / sum;
  bf16x8 o;
#pragma unroll
  for (int j = 0; j < 8; ++j) o[j] = (bf16_t)(e[j] * inv);
  outp[t] = o;
}

// ---------------------------------------------------------------------------
extern "C" void kernel_launch(void* const* d_in, const int* in_sizes, int n_in,
                              void* d_out, int out_size, void* d_ws, size_t ws_size,
                              hipStream_t stream) {
  const int E = 1024, S = 2048, B = 4;
  const int BS = B * S;  // 8192

  const float* x  = (const float*)d_in[0];
  const float* Wq = (const float*)d_in[1];
  const float* bq = (const float*)d_in[2];
  const float* Wk = (const float*)d_in[3];
  const float* bk = (const float*)d_in[4];
  const float* Wv = (const float*)d_in[5];
  const float* bv = (const float*)d_in[6];
  const float* Wo = (const float*)d_in[7];
  const float* bo = (const float*)d_in[8];
  float* out = (float*)d_out;

  char* w = (char*)d_ws;
  const size_t MB = 1ull << 20;
  bf16_t* Wqkvb = (bf16_t*)(w + 0 * MB);          // 6 MB  [3072,1024]
  bf16_t* Wob   = Wqkvb + 3 * E * E;              // 2 MB
  bf16_t* xb    = (bf16_t*)(w + 8 * MB);          // 16 MB [8192,1024]
  bf16_t* QKVb  = (bf16_t*)(w + 24 * MB);         // 48 MB [8192,3072]
  bf16_t* VTb   = (bf16_t*)(w + 72 * MB);         // 16 MB [B][1024,2048]
  bf16_t* Sb    = (bf16_t*)(w + 88 * MB);         // 32 MB scores
  bf16_t* Pb    = (bf16_t*)(w + 8 * MB);          // 32 MB (xb + QKV[0:16MB] dead)
  bf16_t* Ob    = (bf16_t*)(w + 40 * MB);         // 16 MB (QKV[16:32MB] dead)

  // ---- all casts in one dispatch
  {
    const int totalBlocks = ((4 << 18) + (1 << 21)) / 256;  // 12288
    cast_all<<<totalBlocks, 256, 0, stream>>>(
        (const float4*)Wq, (const float4*)Wk, (const float4*)Wv,
        (const float4*)Wo, (const float4*)x, (bf16x4*)Wqkvb, (bf16x4*)xb);
  }

  // ---- fused QKV projection: [8192,3072] = xb . Wqkv^T + (bq|bk|bv)
  gemm256_bt<bf16_t, 3><<<dim3(3 * E / 256, BS / 256, 1), 512, 0, stream>>>(
      xb, Wqkvb, QKVb, bq, bk, bv,
      BS, 3 * E, E, E, E, 3 * E, 1.f, 0, 0, 0);

  // ---- V^T per batch: [2048,1024](ld 3072) -> [1024,2048]
  transpose_bf16<<<dim3(E / 32, S / 32, B), dim3(32, 8), 0, stream>>>(
      QKVb + 2 * E, VTb, S, E, 3 * E, (long long)S * 3 * E, (long long)E * S);

  // ---- scores = Q . K^T * E^-0.5 per batch
  gemm256_bt<bf16_t, 0><<<dim3(S / 256, S / 256, B), 512, 0, stream>>>(
      QKVb, QKVb + E, Sb, nullptr, nullptr, nullptr,
      S, S, E, 3 * E, 3 * E, S, 0.03125f,
      (long long)S * 3 * E, (long long)S * 3 * E, (long long)S * S);

  // ---- softmax
  softmax_rows<<<BS, 256, 0, stream>>>(Sb, Pb, S);

  // ---- O = P . (V^T)^T per batch
  gemm_bt<bf16_t, 0><<<dim3(E / BN, S / BM, B), 256, 0, stream>>>(
      Pb, VTb, Ob, nullptr, nullptr, nullptr,
      S, E, S, S, S, E, 1.f,
      (long long)S * S, (long long)E * S, (long long)S * E);

  // ---- y = O . Wo^T + bo
  gemm_bt<float, 1><<<dim3(E / BN, BS / BM, 1), 256, 0, stream>>>(
      Ob, Wob, out, bo, nullptr, nullptr,
      BS, E, E, E, E, E, 1.f, 0, 0, 0);
}

// Round 2
// 292.485 us; speedup vs baseline: 1.0708x; 1.0708x over previous
//
#include <hip/hip_runtime.h>
#include <hip/hip_bf16.h>

// ---------------------------------------------------------------------------
// SelfAttentionHybrid: single-head attention, B=4 S=2048 E=1024, fp32 in/out.
// R8: gemm256_bt fragment loads moved to inline-asm ds_read_b128 with explicit
// lgkmcnt(0)+sched_barrier(0) fences. Theory: with C++ LDS reads, the compiler
// sees the global_load_lds -> LDS -> ds_read dependency and inserts
// s_waitcnt vmcnt(0) before every phase-0 read, draining the prefetch queue
// each K-tile (R7 measured exactly the 2-phase ~814 TF/round ceiling,
// MfmaUtil 24%). asm reads hide the dependency; ordering is enforced by the
// existing counted vmcnt(8) + raw barriers (wave level) and by rule-18 fences
// (instruction level). Also: epilogue store order j-innermost for 128B
// write-combining (R7 WRITE_SIZE 89MB vs 48MB ideal).
//
// gemm256 schedule per K-tile kt (buf c = kt&1):
//   ph0: ds_read Aq0(8)+Bq0(4);           barrier; lgkm0; MFMA M0xN0; barrier
//   ph1: ds_read Bq1(4);                  barrier; lgkm0; MFMA M0xN1; barrier
//   ph2: ds_read Aq1(8); issue B(kt+2);   barrier; lgkm0; MFMA M1xN1; barrier
//   ph3: issue A(kt+2); MFMA M1xN0 (reg-only); vmcnt(8);           barrier
// Boundary invariant: tile kt+1's 8 loads (issued at kt-1 ph2/ph3) are the
// oldest outstanding; vmcnt(8) retires them while kt+2's 8 stay in flight.
// ---------------------------------------------------------------------------

typedef __bf16 bf16_t;
typedef __bf16 bf16x8 __attribute__((ext_vector_type(8)));
typedef __bf16 bf16x4 __attribute__((ext_vector_type(4)));
typedef float  f32x16 __attribute__((ext_vector_type(16)));
typedef float  f32x4  __attribute__((ext_vector_type(4)));

__device__ __forceinline__ void async_copy16(const void* g, void* l) {
  __builtin_amdgcn_global_load_lds(
      (const __attribute__((address_space(1))) void*)g,
      (__attribute__((address_space(3))) void*)l, 16, 0, 0);
}

// raw workgroup barrier: NO vmcnt/lgkmcnt drain (unlike __syncthreads),
// with compiler-level memory fences so staging/LDS ops can't be moved across.
__device__ __forceinline__ void wg_barrier() {
  asm volatile("" ::: "memory");
  __builtin_amdgcn_s_barrier();
  asm volatile("" ::: "memory");
}

// 32-bit LDS byte address (for asm ds_read; invisible to alias analysis)
__device__ __forceinline__ unsigned lds_addr(const void* p) {
  return (unsigned)(unsigned long long)(__attribute__((address_space(3))) const void*)p;
}

// inline-asm LDS read: compiler cannot see this as an LDS access, so it does
// NOT insert vmcnt(0) ordering vs in-flight global_load_lds prefetches.
// REQUIRES manual s_waitcnt lgkmcnt(0) + sched_barrier(0) before any use.
__device__ __forceinline__ bf16x8 ds_read128(const bf16_t* p) {
  bf16x8 r;
  asm volatile("ds_read_b128 %0, %1" : "=v"(r) : "v"(lds_addr(p)));
  return r;
}

__device__ __forceinline__ f32x4 mfma16(bf16x8 a, bf16x8 b, f32x4 c) {
  return __builtin_amdgcn_mfma_f32_16x16x32_bf16(a, b, c, 0, 0, 0);
}

__device__ __forceinline__ void store_out(float* p, float v)  { *p = v; }
__device__ __forceinline__ void store_out(bf16_t* p, float v) { *p = (bf16_t)v; }

#define BM 128
#define BN 128
#define BKT 64

// ---------------------------------------------------------------------------
// gemm256_bt: C[M,N] = A[M,K](lda) x B[N,K](ldb)^T * scale + bias.
// 512 thr = 8 waves (2Mx4N); wave tile 128x64 = 8x4 frags of 16x16x32 MFMA.
// A-frag: row = lane&15, k = (lane>>4)*8+j. C/D: col = lane&15,
// row = (lane>>4)*4 + reg. LDS [2 buf][256 rows][64 bf16] per matrix; slot
// (r,cc) holds global chunk cc^(r&7); reads use slot kc^(r&7) (involution).
// Requires M%256==0, N%256==0, K%64==0, K>=128, gridDim.y%8==0.
// ---------------------------------------------------------------------------
template <typename OutT, int NBIAS>
__global__ __launch_bounds__(512, 2) void gemm256_bt(
    const bf16_t* __restrict__ A, const bf16_t* __restrict__ B,
    OutT* __restrict__ C,
    const float* __restrict__ b0, const float* __restrict__ b1,
    const float* __restrict__ b2,
    int M, int N, int K, int lda, int ldb, int ldc, float scale,
    long long strideA, long long strideB, long long strideC) {
  const int z = blockIdx.z;
  A += (long long)z * strideA;
  B += (long long)z * strideB;
  C += (long long)z * strideC;

  // L2 supertile remap: 8 y-tiles per supertile, y-fastest inside.
  int bx = blockIdx.x, by = blockIdx.y;
  {
    const int GX  = gridDim.x;
    const int id  = by * GX + bx;
    const int per = GX * 8;
    const int grp = id / per;
    const int rem = id - grp * per;
    by = grp * 8 + (rem & 7);
    bx = rem >> 3;
  }

  __shared__ __align__(16) bf16_t As[2 * 256 * 64];  // 64 KB
  __shared__ __align__(16) bf16_t Bs[2 * 256 * 64];  // 64 KB

  const int t    = threadIdx.x;
  const int lane = t & 63;
  const int w    = t >> 6;
  const int wm   = w & 1;    // M-half of output tile
  const int wn   = w >> 1;   // N-quarter of output tile
  const int g    = lane >> 4;
  const int l7   = lane & 7;
  const int r15  = lane & 15;
  const int tileM = by * 256;
  const int tileN = bx * 256;

  // staging constants: thread covers chunks t and t+512 of each half-tile
  const int row0 = t >> 3;                    // 0..63
  const int gcc  = (t & 7) ^ (row0 & 7);      // swizzled source chunk
  const int dstb = (t & ~63) * 8;             // wave-uniform LDS base (elems)

  // read constants
  const int sw0 = ((0 + g) ^ l7) * 8;         // k-slice 0 chunk offset (elems)
  const int sw1 = ((4 + g) ^ l7) * 8;         // k-slice 1
  const int aRow = (wm * 128 + r15) * 64;
  const int bRow = (wn * 64 + r15) * 64;

  const int NT = K >> 6;

  f32x4 acc[8][4] = {};

  auto stageA = [&](int kt, int h) {
    const int cb = (kt & 1) * 16384;
    const bf16_t* src =
        A + (long long)(tileM + h * 128 + row0) * lda + kt * 64 + gcc * 8;
    bf16_t* dst = &As[cb + h * 8192 + dstb];
    async_copy16(src, dst);
    async_copy16(src + (long long)64 * lda, dst + 4096);
  };
  auto stageB = [&](int kt, int h) {
    const int cb = (kt & 1) * 16384;
    const bf16_t* src =
        B + (long long)(tileN + h * 128 + row0) * ldb + kt * 64 + gcc * 8;
    bf16_t* dst = &Bs[cb + h * 8192 + dstb];
    async_copy16(src, dst);
    async_copy16(src + (long long)64 * ldb, dst + 4096);
  };

  // prologue: tiles 0 (oldest 8 loads) and 1; retire tile 0, keep 1 in flight
  stageA(0, 0); stageA(0, 1); stageB(0, 0); stageB(0, 1);
  stageA(1, 0); stageA(1, 1); stageB(1, 0); stageB(1, 1);
  asm volatile("s_waitcnt vmcnt(8)" ::: "memory");
  wg_barrier();

  bf16x8 a[4][2], bq[2][2][2];

  for (int kt = 0; kt < NT; ++kt) {
    const int cb = (kt & 1) * 16384;
    const int k2 = kt + 2;
    const bf16_t* Ab = &As[cb + aRow];
    const bf16_t* Bb = &Bs[cb + bRow];

    // ---- phase 0: read Aq0 + Bq0; MFMA M-quad0 x N-quad0
#pragma unroll
    for (int i = 0; i < 4; ++i) {
      a[i][0] = ds_read128(Ab + i * 1024 + sw0);
      a[i][1] = ds_read128(Ab + i * 1024 + sw1);
    }
#pragma unroll
    for (int j = 0; j < 2; ++j) {
      bq[0][j][0] = ds_read128(Bb + j * 1024 + sw0);
      bq[0][j][1] = ds_read128(Bb + j * 1024 + sw1);
    }
    wg_barrier();
    asm volatile("s_waitcnt lgkmcnt(0)");
    __builtin_amdgcn_sched_barrier(0);
    __builtin_amdgcn_s_setprio(1);
#pragma unroll
    for (int i = 0; i < 4; ++i)
#pragma unroll
      for (int j = 0; j < 2; ++j) {
        acc[i][j] = mfma16(a[i][0], bq[0][j][0], acc[i][j]);
        acc[i][j] = mfma16(a[i][1], bq[0][j][1], acc[i][j]);
      }
    __builtin_amdgcn_s_setprio(0);
    wg_barrier();

    // ---- phase 1: read Bq1; MFMA M-quad0 x N-quad1
#pragma unroll
    for (int j = 0; j < 2; ++j) {
      bq[1][j][0] = ds_read128(Bb + 2048 + j * 1024 + sw0);
      bq[1][j][1] = ds_read128(Bb + 2048 + j * 1024 + sw1);
    }
    wg_barrier();
    asm volatile("s_waitcnt lgkmcnt(0)");
    __builtin_amdgcn_sched_barrier(0);
    __builtin_amdgcn_s_setprio(1);
#pragma unroll
    for (int i = 0; i < 4; ++i)
#pragma unroll
      for (int j = 0; j < 2; ++j) {
        acc[i][2 + j] = mfma16(a[i][0], bq[1][j][0], acc[i][2 + j]);
        acc[i][2 + j] = mfma16(a[i][1], bq[1][j][1], acc[i][2 + j]);
      }
    __builtin_amdgcn_s_setprio(0);
    wg_barrier();

    // ---- phase 2: read Aq1 (B-slots of this buf now dead -> issue B(kt+2))
#pragma unroll
    for (int i = 0; i < 4; ++i) {
      a[i][0] = ds_read128(Ab + 4096 + i * 1024 + sw0);
      a[i][1] = ds_read128(Ab + 4096 + i * 1024 + sw1);
    }
    if (k2 < NT) { stageB(k2, 0); stageB(k2, 1); }
    wg_barrier();
    asm volatile("s_waitcnt lgkmcnt(0)");
    __builtin_amdgcn_sched_barrier(0);
    __builtin_amdgcn_s_setprio(1);
#pragma unroll
    for (int i = 0; i < 4; ++i)
#pragma unroll
      for (int j = 0; j < 2; ++j) {
        acc[4 + i][2 + j] = mfma16(a[i][0], bq[1][j][0], acc[4 + i][2 + j]);
        acc[4 + i][2 + j] = mfma16(a[i][1], bq[1][j][1], acc[4 + i][2 + j]);
      }
    __builtin_amdgcn_s_setprio(0);
    wg_barrier();

    // ---- phase 3: A-slots dead -> issue A(kt+2); reg-only MFMA; counted wait
    if (k2 < NT) { stageA(k2, 0); stageA(k2, 1); }
    __builtin_amdgcn_s_setprio(1);
#pragma unroll
    for (int i = 0; i < 4; ++i)
#pragma unroll
      for (int j = 0; j < 2; ++j) {
        acc[4 + i][j] = mfma16(a[i][0], bq[0][j][0], acc[4 + i][j]);
        acc[4 + i][j] = mfma16(a[i][1], bq[0][j][1], acc[4 + i][j]);
      }
    __builtin_amdgcn_s_setprio(0);
    // retire tile kt+1's loads; kt+2's 8 loads stay in flight (never drain
    // mid-loop; full drain only when no kt+2 was issued).
    if (k2 < NT) asm volatile("s_waitcnt vmcnt(8)" ::: "memory");
    else         asm volatile("s_waitcnt vmcnt(0)" ::: "memory");
    wg_barrier();
  }

  // epilogue: 16x16 C map: col = lane&15, row = (lane>>4)*4 + r.
  // j innermost: 4 consecutive 32B segments per row -> 128B write-combining.
  float bvv[4];
#pragma unroll
  for (int j = 0; j < 4; ++j) {
    const int col = tileN + wn * 64 + j * 16 + r15;
    float bv = 0.f;
    if (NBIAS == 1) bv = b0[col];
    if (NBIAS == 3) {
      const float* bp = col < 1024 ? b0 : (col < 2048 ? b1 : b2);
      bv = bp[col & 1023];
    }
    bvv[j] = bv;
  }
#pragma unroll
  for (int i = 0; i < 8; ++i) {
#pragma unroll
    for (int r = 0; r < 4; ++r) {
      const long long row = tileM + wm * 128 + i * 16 + g * 4 + r;
      OutT* Crow = C + row * ldc + tileN + wn * 64 + r15;
#pragma unroll
      for (int j = 0; j < 4; ++j)
        store_out(Crow + j * 16, acc[i][j][r] * scale + bvv[j]);
    }
  }
}

// ---------------------------------------------------------------------------
// 128^2 kernel (R6) — kept for PV and output GEMMs (their 256^2 grids would
// be 128 blocks = half the CUs).
// ---------------------------------------------------------------------------
template <typename OutT, int NBIAS>
__global__ __launch_bounds__(256) void gemm_bt(
    const bf16_t* __restrict__ A, const bf16_t* __restrict__ B,
    OutT* __restrict__ C,
    const float* __restrict__ b0, const float* __restrict__ b1,
    const float* __restrict__ b2,
    int M, int N, int K, int lda, int ldb, int ldc, float scale,
    long long strideA, long long strideB, long long strideC) {
  const int z = blockIdx.z;
  A += (long long)z * strideA;
  B += (long long)z * strideB;
  C += (long long)z * strideC;

  int bx = blockIdx.x, by = blockIdx.y;
  {
    const int GX  = gridDim.x;
    const int id  = by * GX + bx;
    const int per = GX * 8;
    const int grp = id / per;
    const int rem = id - grp * per;
    by = grp * 8 + (rem & 7);
    bx = rem >> 3;
  }

  __shared__ __align__(16) bf16_t As[BM * BKT];  // 16 KB
  __shared__ __align__(16) bf16_t Bs[BN * BKT];  // 16 KB

  const int t    = threadIdx.x;
  const int lane = t & 63;
  const int w    = t >> 6;
  const int wm   = w & 1;
  const int wn   = w >> 1;
  const int tileM = by * BM;
  const int tileN = bx * BN;

  f32x16 acc[2][2] = {};

  for (int k0 = 0; k0 < K; k0 += BKT) {
#pragma unroll
    for (int i = 0; i < 4; ++i) {
      const int c   = t + 256 * i;
      const int row = c >> 3;
      const int cc  = c & 7;
      const int gcc = cc ^ (row & 7);
      const int ldsbase = ((t & ~63) + 256 * i) * 8;
      async_copy16(A + (long long)(tileM + row) * lda + k0 + gcc * 8, &As[ldsbase]);
      async_copy16(B + (long long)(tileN + row) * ldb + k0 + gcc * 8, &Bs[ldsbase]);
    }
    __syncthreads();

#pragma unroll
    for (int s = 0; s < 4; ++s) {
      const int kc = s + 4 * (lane >> 5);
      bf16x8 af[2], bfr[2];
#pragma unroll
      for (int ti = 0; ti < 2; ++ti) {
        const int row = wm * 64 + ti * 32 + (lane & 31);
        af[ti] = *(const bf16x8*)&As[row * BKT + ((kc ^ (row & 7)) * 8)];
      }
#pragma unroll
      for (int tj = 0; tj < 2; ++tj) {
        const int row = wn * 64 + tj * 32 + (lane & 31);
        bfr[tj] = *(const bf16x8*)&Bs[row * BKT + ((kc ^ (row & 7)) * 8)];
      }
#pragma unroll
      for (int ti = 0; ti < 2; ++ti)
#pragma unroll
        for (int tj = 0; tj < 2; ++tj)
          acc[ti][tj] = __builtin_amdgcn_mfma_f32_32x32x16_bf16(
              af[ti], bfr[tj], acc[ti][tj], 0, 0, 0);
    }
    __syncthreads();
  }

#pragma unroll
  for (int tj = 0; tj < 2; ++tj) {
    const int col = tileN + wn * 64 + tj * 32 + (lane & 31);
    float bv = 0.f;
    if (NBIAS == 1) bv = b0[col];
    if (NBIAS == 3) {
      const float* bp = col < 1024 ? b0 : (col < 2048 ? b1 : b2);
      bv = bp[col & 1023];
    }
#pragma unroll
    for (int ti = 0; ti < 2; ++ti) {
      const int rowb = tileM + wm * 64 + ti * 32 + 4 * (lane >> 5);
#pragma unroll
      for (int r = 0; r < 16; ++r) {
        const int row = rowb + (r & 3) + 8 * (r >> 2);
        store_out(&C[(long long)row * ldc + col], acc[ti][tj][r] * scale + bv);
      }
    }
  }
}

// ---------------------------------------------------------------------------
// fused cast: all 4 weights + x in one dispatch (flat grid, region decode).
// ---------------------------------------------------------------------------
__global__ __launch_bounds__(256) void cast_all(
    const float4* __restrict__ w0, const float4* __restrict__ w1,
    const float4* __restrict__ w2, const float4* __restrict__ w3,
    const float4* __restrict__ x,
    bf16x4* __restrict__ wdst, bf16x4* __restrict__ xdst) {
  const int N4W = 1 << 18;  // 1024*1024/4
  const int id = blockIdx.x * 256 + threadIdx.x;
  const float4* src;
  bf16x4* dst;
  if (id < 4 * N4W) {
    const int z = id >> 18;
    src = (z == 0 ? w0 : z == 1 ? w1 : z == 2 ? w2 : w3) + (id & (N4W - 1));
    dst = wdst + id;
  } else {
    const int i = id - 4 * N4W;
    src = x + i;
    dst = xdst + i;
  }
  const float4 v = *src;
  bf16x4 o;
  o[0] = (bf16_t)v.x; o[1] = (bf16_t)v.y; o[2] = (bf16_t)v.z; o[3] = (bf16_t)v.w;
  *dst = o;
}

// ---------------------------------------------------------------------------
// bf16 transpose [R,C](ldin) -> [C,R], batched via blockIdx.z
// ---------------------------------------------------------------------------
__global__ __launch_bounds__(256) void transpose_bf16(
    const bf16_t* __restrict__ in, bf16_t* __restrict__ out, int R, int C,
    int ldin, long long sIn, long long sOut) {
  in  += (long long)blockIdx.z * sIn;
  out += (long long)blockIdx.z * sOut;
  __shared__ bf16_t tile[32][33];
  const int tx = threadIdx.x, ty = threadIdx.y;
  const int x = blockIdx.x * 32 + tx;
  const int y0 = blockIdx.y * 32;
#pragma unroll
  for (int j = 0; j < 32; j += 8)
    tile[ty + j][tx] = in[(long long)(y0 + ty + j) * ldin + x];
  __syncthreads();
  const int x2 = y0 + tx;
  const int y2 = blockIdx.x * 32;
#pragma unroll
  for (int j = 0; j < 32; j += 8)
    out[(long long)(y2 + ty + j) * R + x2] = tile[tx][ty + j];
}

// ---------------------------------------------------------------------------
// row softmax: 2048-wide rows, 256 threads x 8 elems
// ---------------------------------------------------------------------------
__global__ __launch_bounds__(256) void softmax_rows(
    const bf16_t* __restrict__ S, bf16_t* __restrict__ P, int cols) {
  const long long row = blockIdx.x;
  const bf16x8* inp = (const bf16x8*)(S + row * cols);
  bf16x8* outp      = (bf16x8*)(P + row * cols);
  const int t = threadIdx.x;
  const int w = t >> 6, lane = t & 63;

  const bf16x8 v = inp[t];
  float f[8];
#pragma unroll
  for (int j = 0; j < 8; ++j) f[j] = (float)v[j];

  float m = f[0];
#pragma unroll
  for (int j = 1; j < 8; ++j) m = fmaxf(m, f[j]);
#pragma unroll
  for (int off = 32; off > 0; off >>= 1) m = fmaxf(m, __shfl_xor(m, off));

  __shared__ float red[8];
  if (lane == 0) red[w] = m;
  __syncthreads();
  m = fmaxf(fmaxf(red[0], red[1]), fmaxf(red[2], red[3]));

  float e[8], sum = 0.f;
#pragma unroll
  for (int j = 0; j < 8; ++j) { e[j] = __expf(f[j] - m); sum += e[j]; }
#pragma unroll
  for (int off = 32; off > 0; off >>= 1) sum += __shfl_xor(sum, off);
  if (lane == 0) red[4 + w] = sum;
  __syncthreads();
  sum = red[4] + red[5] + red[6] + red[7];

  const float inv = 1.f / sum;
  bf16x8 o;
#pragma unroll
  for (int j = 0; j < 8; ++j) o[j] = (bf16_t)(e[j] * inv);
  outp[t] = o;
}

// ---------------------------------------------------------------------------
extern "C" void kernel_launch(void* const* d_in, const int* in_sizes, int n_in,
                              void* d_out, int out_size, void* d_ws, size_t ws_size,
                              hipStream_t stream) {
  const int E = 1024, S = 2048, B = 4;
  const int BS = B * S;  // 8192

  const float* x  = (const float*)d_in[0];
  const float* Wq = (const float*)d_in[1];
  const float* bq = (const float*)d_in[2];
  const float* Wk = (const float*)d_in[3];
  const float* bk = (const float*)d_in[4];
  const float* Wv = (const float*)d_in[5];
  const float* bv = (const float*)d_in[6];
  const float* Wo = (const float*)d_in[7];
  const float* bo = (const float*)d_in[8];
  float* out = (float*)d_out;

  char* w = (char*)d_ws;
  const size_t MB = 1ull << 20;
  bf16_t* Wqkvb = (bf16_t*)(w + 0 * MB);          // 6 MB  [3072,1024]
  bf16_t* Wob   = Wqkvb + 3 * E * E;              // 2 MB
  bf16_t* xb    = (bf16_t*)(w + 8 * MB);          // 16 MB [8192,1024]
  bf16_t* QKVb  = (bf16_t*)(w + 24 * MB);         // 48 MB [8192,3072]
  bf16_t* VTb   = (bf16_t*)(w + 72 * MB);         // 16 MB [B][1024,2048]
  bf16_t* Sb    = (bf16_t*)(w + 88 * MB);         // 32 MB scores
  bf16_t* Pb    = (bf16_t*)(w + 8 * MB);          // 32 MB (xb + QKV[0:16MB] dead)
  bf16_t* Ob    = (bf16_t*)(w + 40 * MB);         // 16 MB (QKV[16:32MB] dead)

  // ---- all casts in one dispatch
  {
    const int totalBlocks = ((4 << 18) + (1 << 21)) / 256;  // 12288
    cast_all<<<totalBlocks, 256, 0, stream>>>(
        (const float4*)Wq, (const float4*)Wk, (const float4*)Wv,
        (const float4*)Wo, (const float4*)x, (bf16x4*)Wqkvb, (bf16x4*)xb);
  }

  // ---- fused QKV projection: [8192,3072] = xb . Wqkv^T + (bq|bk|bv)
  gemm256_bt<bf16_t, 3><<<dim3(3 * E / 256, BS / 256, 1), 512, 0, stream>>>(
      xb, Wqkvb, QKVb, bq, bk, bv,
      BS, 3 * E, E, E, E, 3 * E, 1.f, 0, 0, 0);

  // ---- V^T per batch: [2048,1024](ld 3072) -> [1024,2048]
  transpose_bf16<<<dim3(E / 32, S / 32, B), dim3(32, 8), 0, stream>>>(
      QKVb + 2 * E, VTb, S, E, 3 * E, (long long)S * 3 * E, (long long)E * S);

  // ---- scores = Q . K^T * E^-0.5 per batch
  gemm256_bt<bf16_t, 0><<<dim3(S / 256, S / 256, B), 512, 0, stream>>>(
      QKVb, QKVb + E, Sb, nullptr, nullptr, nullptr,
      S, S, E, 3 * E, 3 * E, S, 0.03125f,
      (long long)S * 3 * E, (long long)S * 3 * E, (long long)S * S);

  // ---- softmax
  softmax_rows<<<BS, 256, 0, stream>>>(Sb, Pb, S);

  // ---- O = P . (V^T)^T per batch
  gemm_bt<bf16_t, 0><<<dim3(E / BN, S / BM, B), 256, 0, stream>>>(
      Pb, VTb, Ob, nullptr, nullptr, nullptr,
      S, E, S, S, S, E, 1.f,
      (long long)S * S, (long long)E * S, (long long)S * E);

  // ---- y = O . Wo^T + bo
  gemm_bt<float, 1><<<dim3(E / BN, BS / BM, 1), 256, 0, stream>>>(
      Ob, Wob, out, bo, nullptr, nullptr,
      BS, E, E, E, E, E, 1.f, 0, 0, 0);
}